// Round 9
// baseline (128.346 us; speedup 1.0000x reference)
//
#include <hip/hip_runtime.h>
#include <hip/hip_bf16.h>

// ConvolutionalSelfAttention — algebraically reduced:
//   Kn[b,n,:] = normalize(x[b,n,:] @ key_w^T + key_b)      (bf16, via MFMA)
//   Qn[b,m,:] = normalize(x[b,m,:] @ query_w^T + query_b)  (bf16, via MFMA)
//   v[b,n]    = x[b,n,:] @ value_w^T + value_b             (fp32)
//   S[b,n,m]  = Kn[b,n]·Qn[b,m]   (|S|<=1, exp stable without max-sub)
//   R[b,m]    = (sum_n v e^S) / (sum_n e^S)                (fused, S never stored)
//   out[b,c,i,j] = 3x3 box sum of R[b,m]*batch[b,c,m]  (fp32, L3-resident)
// local_indices unused (windows are complete 3x3, order-invariant).
//
// R14: drop the xc bf16 batch copy. R11/R12/R13 (occupancy x2, de-phasing)
//  were ALL neutral at ~127 -> fused_lin is near its traffic+issue floor,
//  not structure-bound. Remaining lever: write volume. xc was 8 MB of
//  fused_lin's 24.6 MB write tail, and exists only so out_kernel reads
//  bf16; but batch (16.8 MB fp32) is L3-resident anyway. out_kernel now
//  reads batch directly (L3-served), fused_lin drops the xc stores.
//  Accuracy strictly improves (P uses exact fp32 x).
//  fused_lin structure = R13 (single-stage, barrier-free MFMA section).
// ws: Kn 8MB | Qn 8MB | kpk 128KB | qpk 128KB | v 64KB | R 64KB

#define NB 16
#define NC 256
#define NHW 1024
#define NCH 30

typedef __attribute__((ext_vector_type(8))) short short8;
typedef __attribute__((ext_vector_type(4))) float f32x4;

static __device__ __forceinline__ unsigned short f2bf(float f) {
    __hip_bfloat16 h = __float2bfloat16(f);
    return *(unsigned short*)&h;
}

// fp32 [co][ci] weights -> bf16 MFMA B-fragment order.
// Fragment (g 0..7 = k-chunk of 32, ct 0..15 = co block of 16):
//   dst[((g*16+ct)*64 + lane)*8 + j] = bf16(W[ct*16 + (lane&15)][g*32 + (lane>>4)*8 + j])
// so the hot kernel's per-(g,ct) load is base + lane*16B — fully coalesced.
__global__ __launch_bounds__(256) void wconv_kernel(
    const float* __restrict__ key_w, const float* __restrict__ query_w,
    unsigned short* __restrict__ kpk, unsigned short* __restrict__ qpk)
{
    const int gx = blockIdx.x;            // 16 blocks: [mat | g]
    const int mat = gx >> 3, g = gx & 7, t = threadIdx.x;
    const float* src = mat ? query_w : key_w;
    unsigned short* dst = mat ? qpk : kpk;
    #pragma unroll
    for (int it = 0; it < 4; ++it) {
        int idx = it * 256 + t;           // 0..1023 = ct*64 + lane
        int ct = idx >> 6, lane = idx & 63;
        int l15 = lane & 15, q = lane >> 4;
        const float* s = src + (ct * 16 + l15) * NC + g * 32 + q * 8;
        float4 a = *(const float4*)s;
        float4 c = *(const float4*)(s + 4);
        short8 o;
        o[0] = (short)f2bf(a.x); o[1] = (short)f2bf(a.y);
        o[2] = (short)f2bf(a.z); o[3] = (short)f2bf(a.w);
        o[4] = (short)f2bf(c.x); o[5] = (short)f2bf(c.y);
        o[6] = (short)f2bf(c.z); o[7] = (short)f2bf(c.w);
        *(short8*)(dst + ((size_t)(g * 16 + ct) * 64 + lane) * 8) = o;
    }
}

// Fused: transpose batch -> LDS bf16 tile + v + MFMA linears + row-normalize
// -> Kn, Qn.
// Grid (32 n-tiles of 32, B), 512 threads = 8 waves; wave = co-eighth (32 co),
// 2 n-fragments per wave. Single-stage: issue 4 loads -> weight prologue ->
// consume -> 1 barrier -> 8 unrolled barrier-free MFMA chunks (depth-2 wpf).
__global__ __launch_bounds__(512, 4) void fused_lin_kernel(
    const float* __restrict__ batch,
    const float* __restrict__ value_w, const float* __restrict__ value_b,
    const unsigned short* __restrict__ kpk, const unsigned short* __restrict__ qpk,
    const float* __restrict__ key_b, const float* __restrict__ query_b,
    unsigned short* __restrict__ Kn, unsigned short* __restrict__ Qn,
    float* __restrict__ vout)
{
    const int b = blockIdx.y, n0 = blockIdx.x * 32;
    const int t = threadIdx.x, wave = t >> 6, lane = t & 63;
    const int l15 = lane & 15, quad = lane >> 4;

    __shared__ unsigned short Xs[32][264];     // [n][c], stride 528 B (16B-mult)
    __shared__ float PK[8][2][16], PQ[8][2][16];
    __shared__ float4 vred[8][8];

    // staging role: thread owns c rows {c_l, c_l+64, c_l+128, c_l+192}, 4 n's
    const int c_l = t >> 3;                  // 0..63
    const int n4  = (t & 7) * 4;             // 0..28
    const float* bb = batch + (size_t)b * NC * NHW + n0;
    float4 vacc = {0.f, 0.f, 0.f, 0.f};

    // ISSUE all 4 staging loads back-to-back (one latency exposure)
    float4 xs0 = *(const float4*)(bb + (size_t)(c_l      ) * NHW + n4);
    float4 xs1 = *(const float4*)(bb + (size_t)(c_l +  64) * NHW + n4);
    float4 xs2 = *(const float4*)(bb + (size_t)(c_l + 128) * NHW + n4);
    float4 xs3 = *(const float4*)(bb + (size_t)(c_l + 192) * NHW + n4);

    // packed-weight base for this wave's co eighth (frag = wave*2 + ct)
    const unsigned short* kbase = kpk + (size_t)(wave * 2) * 512 + lane * 8;
    const unsigned short* qbase = qpk + (size_t)(wave * 2) * 512 + lane * 8;

    // weight prologue: chunks 0,1 -> bufs 0,1 (overlaps staging latency)
    short8 wK[3][2], wQ[3][2];
    #pragma unroll
    for (int ct = 0; ct < 2; ++ct) {
        wK[0][ct] = *(const short8*)(kbase + ct * 512);
        wQ[0][ct] = *(const short8*)(qbase + ct * 512);
        wK[1][ct] = *(const short8*)(kbase + 8192 + ct * 512);
        wQ[1][ct] = *(const short8*)(qbase + 8192 + ct * 512);
    }

    // CONSUME staging: convert, v-acc, LDS write
    #define CONSUME(XS, CI)                                                  \
    {                                                                        \
        int c0 = (CI) + c_l;                                                 \
        ushort4 o0;                                                          \
        o0.x = f2bf(XS.x); o0.y = f2bf(XS.y);                                \
        o0.z = f2bf(XS.z); o0.w = f2bf(XS.w);                                \
        float w0 = value_w[c0];                                              \
        vacc.x += XS.x * w0; vacc.y += XS.y * w0;                            \
        vacc.z += XS.z * w0; vacc.w += XS.w * w0;                            \
        Xs[n4 + 0][c0] = o0.x; Xs[n4 + 1][c0] = o0.y;                        \
        Xs[n4 + 2][c0] = o0.z; Xs[n4 + 3][c0] = o0.w;                        \
    }
    CONSUME(xs0, 0)
    CONSUME(xs1, 64)
    CONSUME(xs2, 128)
    CONSUME(xs3, 192)
    #undef CONSUME
    __syncthreads();

    f32x4 accK[2][2], accQ[2][2];            // [ns][ct]
    #pragma unroll
    for (int ct = 0; ct < 2; ++ct) {
        int co = wave * 32 + ct * 16 + l15;
        float bK = key_b[co], bQ = query_b[co];
        accK[0][ct] = (f32x4){bK, bK, bK, bK};
        accK[1][ct] = (f32x4){bK, bK, bK, bK};
        accQ[0][ct] = (f32x4){bQ, bQ, bQ, bQ};
        accQ[1][ct] = (f32x4){bQ, bQ, bQ, bQ};
    }

    // 8 k-chunks, fully unrolled, no barriers; depth-2 weight prefetch
    #pragma unroll
    for (int g = 0; g < 8; ++g) {
        if (g < 6) {
            const int nb_ = (g + 2) % 3;
            #pragma unroll
            for (int ct = 0; ct < 2; ++ct) {
                wK[nb_][ct] = *(const short8*)(kbase + (g + 2) * 8192 + ct * 512);
                wQ[nb_][ct] = *(const short8*)(qbase + (g + 2) * 8192 + ct * 512);
            }
        }
        short8 af0 = *(const short8*)&Xs[l15][g * 32 + quad * 8];
        short8 af1 = *(const short8*)&Xs[16 + l15][g * 32 + quad * 8];
        const int cb = g % 3;
        #pragma unroll
        for (int ct = 0; ct < 2; ++ct) {
            accK[0][ct] = __builtin_amdgcn_mfma_f32_16x16x32_bf16(af0, wK[cb][ct], accK[0][ct], 0, 0, 0);
            accK[1][ct] = __builtin_amdgcn_mfma_f32_16x16x32_bf16(af1, wK[cb][ct], accK[1][ct], 0, 0, 0);
            accQ[0][ct] = __builtin_amdgcn_mfma_f32_16x16x32_bf16(af0, wQ[cb][ct], accQ[0][ct], 0, 0, 0);
            accQ[1][ct] = __builtin_amdgcn_mfma_f32_16x16x32_bf16(af1, wQ[cb][ct], accQ[1][ct], 0, 0, 0);
        }
    }

    // v: c_l = wave*8 + (lane>>3) -> reduce over lane bits 3..5, waves via LDS
    #pragma unroll
    for (int o = 8; o <= 32; o <<= 1) {
        vacc.x += __shfl_xor(vacc.x, o, 64); vacc.y += __shfl_xor(vacc.y, o, 64);
        vacc.z += __shfl_xor(vacc.z, o, 64); vacc.w += __shfl_xor(vacc.w, o, 64);
    }

    // row-norm partials: rows n = n0 + ns*16 + quad*4 + r, this wave's 32 co
    float nK[2][4] = {{0, 0, 0, 0}, {0, 0, 0, 0}};
    float nQ[2][4] = {{0, 0, 0, 0}, {0, 0, 0, 0}};
    #pragma unroll
    for (int ns = 0; ns < 2; ++ns)
        #pragma unroll
        for (int ct = 0; ct < 2; ++ct)
            #pragma unroll
            for (int r = 0; r < 4; ++r) {
                nK[ns][r] += accK[ns][ct][r] * accK[ns][ct][r];
                nQ[ns][r] += accQ[ns][ct][r] * accQ[ns][ct][r];
            }
    #pragma unroll
    for (int ns = 0; ns < 2; ++ns)
        #pragma unroll
        for (int r = 0; r < 4; ++r)
            #pragma unroll
            for (int o = 1; o < 16; o <<= 1) {
                nK[ns][r] += __shfl_xor(nK[ns][r], o, 64);
                nQ[ns][r] += __shfl_xor(nQ[ns][r], o, 64);
            }
    if (l15 == 0)
        #pragma unroll
        for (int ns = 0; ns < 2; ++ns)
            #pragma unroll
            for (int r = 0; r < 4; ++r) {
                PK[wave][ns][quad * 4 + r] = nK[ns][r];
                PQ[wave][ns][quad * 4 + r] = nQ[ns][r];
            }
    if (lane < 8) vred[wave][lane] = vacc;
    __syncthreads();

    float ik[2][4], iq[2][4];
    #pragma unroll
    for (int ns = 0; ns < 2; ++ns)
        #pragma unroll
        for (int r = 0; r < 4; ++r) {
            int qr = quad * 4 + r;
            float sk = 0.f, sq = 0.f;
            #pragma unroll
            for (int w = 0; w < 8; ++w) { sk += PK[w][ns][qr]; sq += PQ[w][ns][qr]; }
            ik[ns][r] = 1.f / fmaxf(sqrtf(sk), 1e-12f);
            iq[ns][r] = 1.f / fmaxf(sqrtf(sq), 1e-12f);
        }
    #pragma unroll
    for (int ns = 0; ns < 2; ++ns)
        #pragma unroll
        for (int ct = 0; ct < 2; ++ct)
            #pragma unroll
            for (int r = 0; r < 4; ++r) {
                size_t row = (size_t)(b * NHW + n0 + ns * 16 + quad * 4 + r) * NC
                           + wave * 32 + ct * 16 + l15;
                Kn[row] = f2bf(accK[ns][ct][r] * ik[ns][r]);
                Qn[row] = f2bf(accQ[ns][ct][r] * iq[ns][r]);
            }
    if (t < 8) {
        float4 s = {0.f, 0.f, 0.f, 0.f};
        #pragma unroll
        for (int w = 0; w < 8; ++w) {
            float4 p = vred[w][t];
            s.x += p.x; s.y += p.y; s.z += p.z; s.w += p.w;
        }
        float vb = value_b[0];
        s.x += vb; s.y += vb; s.z += vb; s.w += vb;
        *(float4*)(vout + b * NHW + n0 + t * 4) = s;
    }
}

// Per (b, 64 m-cols): 8 waves each own an n-eighth; per-iter 32 MFMAs in
// 8 independent depth-4 chains. Halves Kn L2 redundancy vs m-tile 32.
__global__ __launch_bounds__(512) void attn_kernel(
    const unsigned short* __restrict__ Kn,
    const unsigned short* __restrict__ Qn,
    const float* __restrict__ vbuf,
    float* __restrict__ R)
{
    const int b = blockIdx.y, m0 = blockIdx.x * 64;
    const int t = threadIdx.x, wave = t >> 6, lane = t & 63;
    const int l15 = lane & 15, quad = lane >> 4;

    short8 bf[4][8];
    #pragma unroll
    for (int ms = 0; ms < 4; ++ms) {
        const short* q = (const short*)Qn
                       + (size_t)(b * NHW + m0 + ms * 16 + l15) * NC + quad * 8;
        #pragma unroll
        for (int c = 0; c < 8; ++c) bf[ms][c] = *(const short8*)(q + 32 * c);
    }
    const float* vb = vbuf + b * NHW;
    const int nstart = wave * 128;
    const short* ka = (const short*)Kn + (size_t)(b * NHW + nstart + l15) * NC + quad * 8;

    float z[4] = {0.f, 0.f, 0.f, 0.f}, tc[4] = {0.f, 0.f, 0.f, 0.f};
    for (int it = 0; it < 8; ++it, ka += 16 * NC) {
        short8 af[8];
        #pragma unroll
        for (int c = 0; c < 8; ++c) af[c] = *(const short8*)(ka + 32 * c);
        f32x4 a0[4], a1[4];
        #pragma unroll
        for (int ms = 0; ms < 4; ++ms) { a0[ms] = (f32x4){0,0,0,0}; a1[ms] = (f32x4){0,0,0,0}; }
        #pragma unroll
        for (int c = 0; c < 4; ++c)
            #pragma unroll
            for (int ms = 0; ms < 4; ++ms) {
                a0[ms] = __builtin_amdgcn_mfma_f32_16x16x32_bf16(af[c],     bf[ms][c],     a0[ms], 0, 0, 0);
                a1[ms] = __builtin_amdgcn_mfma_f32_16x16x32_bf16(af[c + 4], bf[ms][c + 4], a1[ms], 0, 0, 0);
            }
        float4 vv = *(const float4*)(vb + nstart + it * 16 + quad * 4);
        #pragma unroll
        for (int ms = 0; ms < 4; ++ms)
            #pragma unroll
            for (int r = 0; r < 4; ++r) {
                float e = __expf(a0[ms][r] + a1[ms][r]);
                z[ms] += e;
                tc[ms] += ((const float*)&vv)[r] * e;
            }
    }
    #pragma unroll
    for (int ms = 0; ms < 4; ++ms) {
        z[ms]  += __shfl_xor(z[ms], 16, 64);  z[ms]  += __shfl_xor(z[ms], 32, 64);
        tc[ms] += __shfl_xor(tc[ms], 16, 64); tc[ms] += __shfl_xor(tc[ms], 32, 64);
    }

    __shared__ float zs[8][4][16], ts[8][4][16];
    if (lane < 16)
        #pragma unroll
        for (int ms = 0; ms < 4; ++ms) {
            zs[wave][ms][l15] = z[ms];
            ts[wave][ms][l15] = tc[ms];
        }
    __syncthreads();
    if (t < 64) {
        int ms = t >> 4, li = t & 15;
        float zz = 0.f, tt = 0.f;
        #pragma unroll
        for (int w = 0; w < 8; ++w) { zz += zs[w][ms][li]; tt += ts[w][ms][li]; }
        R[b * NHW + m0 + ms * 16 + li] = tt / zz;
    }
}

// out[b,c,i,j] = 3x3 box sum over P[m] = R[b,m]*batch[b,c,m]  (fp32, L3-hot)
__global__ __launch_bounds__(256) void out_kernel(
    const float* __restrict__ batch,
    const float* __restrict__ R,
    float* __restrict__ out)
{
    const int bc = blockIdx.x;
    const int b  = bc >> 8;
    const int t  = threadIdx.x;
    __shared__ float P[NHW];

    const float* xp = batch + (size_t)bc * NHW;
    const float* rp = R + b * NHW;
    {
        float4 xv = *(const float4*)(xp + t * 4);
        float4 rv = *(const float4*)(rp + t * 4);
        P[t * 4 + 0] = rv.x * xv.x;
        P[t * 4 + 1] = rv.y * xv.y;
        P[t * 4 + 2] = rv.z * xv.z;
        P[t * 4 + 3] = rv.w * xv.w;
    }
    __syncthreads();
    for (int idx = t; idx < NCH * NCH; idx += 256) {
        int i = idx / NCH, j = idx - i * NCH;
        const float* pr = &P[i * 32 + j];
        float s = pr[0]  + pr[1]  + pr[2]
                + pr[32] + pr[33] + pr[34]
                + pr[64] + pr[65] + pr[66];
        out[(size_t)bc * (NCH * NCH) + idx] = s;
    }
}

extern "C" void kernel_launch(void* const* d_in, const int* in_sizes, int n_in,
                              void* d_out, int out_size, void* d_ws, size_t ws_size,
                              hipStream_t stream) {
    const float* batch   = (const float*)d_in[0];
    const float* key_w   = (const float*)d_in[1];
    const float* key_b   = (const float*)d_in[2];
    const float* query_w = (const float*)d_in[3];
    const float* query_b = (const float*)d_in[4];
    const float* value_w = (const float*)d_in[5];
    const float* value_b = (const float*)d_in[6];
    float* out = (float*)d_out;

    char* ws = (char*)d_ws;
    const size_t KQ = (size_t)NB * NHW * NC;            // 4,194,304 elems
    unsigned short* Kn  = (unsigned short*)ws;                        // 8MB
    unsigned short* Qn  = Kn + KQ;                                    // 8MB
    unsigned short* kpk = Qn + KQ;                                    // 128KB
    unsigned short* qpk = kpk + NC * NC;                              // 128KB
    float* vbuf = (float*)(qpk + NC * NC);                            // 64KB
    float* Rbuf = vbuf + NB * NHW;                                    // 64KB

    wconv_kernel<<<16, 256, 0, stream>>>(key_w, query_w, kpk, qpk);
    fused_lin_kernel<<<dim3(32, NB), 512, 0, stream>>>(batch, value_w, value_b,
                                                       kpk, qpk, key_b, query_b,
                                                       Kn, Qn, vbuf);
    attn_kernel<<<dim3(16, NB), 512, 0, stream>>>(Kn, Qn, vbuf, Rbuf);
    out_kernel<<<NB * NC, 256, 0, stream>>>(batch, Rbuf, out);
}

// Round 10
// 127.258 us; speedup vs baseline: 1.0086x; 1.0086x over previous
//
#include <hip/hip_runtime.h>
#include <hip/hip_bf16.h>

// ConvolutionalSelfAttention — algebraically reduced:
//   Kn[b,n,:] = normalize(x[b,n,:] @ key_w^T + key_b)      (bf16, via MFMA)
//   Qn[b,m,:] = normalize(x[b,m,:] @ query_w^T + query_b)  (bf16, via MFMA)
//   v[b,n]    = x[b,n,:] @ value_w^T + value_b             (fp32)
//   S[b,n,m]  = Kn[b,n]·Qn[b,m]   (|S|<=1, exp stable without max-sub)
//   R[b,m]    = (sum_n v e^S) / (sum_n e^S)                (fused, S never stored)
//   out[b,c,i,j] = 3x3 box sum of R[b,m]*batch[b,c,m]  (fp32, L3-resident)
// local_indices unused (windows are complete 3x3, order-invariant).
//
// R15: XCD-aware swizzle for attn. Each of b's 16 m-blocks reads ALL of
//  Kn[b] (512 KB): 128 MB aggregate re-read. Default round-robin dispatch
//  sprays them over 8 XCDs -> each XCD's L2 refetches Kn[b] from L3. Swizzle
//  (XCD = i%8): b = 2*(i&7)+(i>>7), m = (i>>3)&15 pins all 16 m-blocks of a
//  b to ONE XCD (2 b's/XCD) -> Kn[b]+Qn[b] = 1 MB resident in that XCD's
//  4 MB L2; 15 of 16 reads become L2 hits. Bijective, correctness-neutral.
//  fused_lin/out/wconv unchanged (R14).
// ws: Kn 8MB | Qn 8MB | kpk 128KB | qpk 128KB | v 64KB | R 64KB

#define NB 16
#define NC 256
#define NHW 1024
#define NCH 30

typedef __attribute__((ext_vector_type(8))) short short8;
typedef __attribute__((ext_vector_type(4))) float f32x4;

static __device__ __forceinline__ unsigned short f2bf(float f) {
    __hip_bfloat16 h = __float2bfloat16(f);
    return *(unsigned short*)&h;
}

// fp32 [co][ci] weights -> bf16 MFMA B-fragment order.
// Fragment (g 0..7 = k-chunk of 32, ct 0..15 = co block of 16):
//   dst[((g*16+ct)*64 + lane)*8 + j] = bf16(W[ct*16 + (lane&15)][g*32 + (lane>>4)*8 + j])
// so the hot kernel's per-(g,ct) load is base + lane*16B — fully coalesced.
__global__ __launch_bounds__(256) void wconv_kernel(
    const float* __restrict__ key_w, const float* __restrict__ query_w,
    unsigned short* __restrict__ kpk, unsigned short* __restrict__ qpk)
{
    const int gx = blockIdx.x;            // 16 blocks: [mat | g]
    const int mat = gx >> 3, g = gx & 7, t = threadIdx.x;
    const float* src = mat ? query_w : key_w;
    unsigned short* dst = mat ? qpk : kpk;
    #pragma unroll
    for (int it = 0; it < 4; ++it) {
        int idx = it * 256 + t;           // 0..1023 = ct*64 + lane
        int ct = idx >> 6, lane = idx & 63;
        int l15 = lane & 15, q = lane >> 4;
        const float* s = src + (ct * 16 + l15) * NC + g * 32 + q * 8;
        float4 a = *(const float4*)s;
        float4 c = *(const float4*)(s + 4);
        short8 o;
        o[0] = (short)f2bf(a.x); o[1] = (short)f2bf(a.y);
        o[2] = (short)f2bf(a.z); o[3] = (short)f2bf(a.w);
        o[4] = (short)f2bf(c.x); o[5] = (short)f2bf(c.y);
        o[6] = (short)f2bf(c.z); o[7] = (short)f2bf(c.w);
        *(short8*)(dst + ((size_t)(g * 16 + ct) * 64 + lane) * 8) = o;
    }
}

// Fused: transpose batch -> LDS bf16 tile + v + MFMA linears + row-normalize
// -> Kn, Qn.
// Grid (32 n-tiles of 32, B), 512 threads = 8 waves; wave = co-eighth (32 co),
// 2 n-fragments per wave. Single-stage: issue 4 loads -> weight prologue ->
// consume -> 1 barrier -> 8 unrolled barrier-free MFMA chunks (depth-2 wpf).
__global__ __launch_bounds__(512, 4) void fused_lin_kernel(
    const float* __restrict__ batch,
    const float* __restrict__ value_w, const float* __restrict__ value_b,
    const unsigned short* __restrict__ kpk, const unsigned short* __restrict__ qpk,
    const float* __restrict__ key_b, const float* __restrict__ query_b,
    unsigned short* __restrict__ Kn, unsigned short* __restrict__ Qn,
    float* __restrict__ vout)
{
    const int b = blockIdx.y, n0 = blockIdx.x * 32;
    const int t = threadIdx.x, wave = t >> 6, lane = t & 63;
    const int l15 = lane & 15, quad = lane >> 4;

    __shared__ unsigned short Xs[32][264];     // [n][c], stride 528 B (16B-mult)
    __shared__ float PK[8][2][16], PQ[8][2][16];
    __shared__ float4 vred[8][8];

    // staging role: thread owns c rows {c_l, c_l+64, c_l+128, c_l+192}, 4 n's
    const int c_l = t >> 3;                  // 0..63
    const int n4  = (t & 7) * 4;             // 0..28
    const float* bb = batch + (size_t)b * NC * NHW + n0;
    float4 vacc = {0.f, 0.f, 0.f, 0.f};

    // ISSUE all 4 staging loads back-to-back (one latency exposure)
    float4 xs0 = *(const float4*)(bb + (size_t)(c_l      ) * NHW + n4);
    float4 xs1 = *(const float4*)(bb + (size_t)(c_l +  64) * NHW + n4);
    float4 xs2 = *(const float4*)(bb + (size_t)(c_l + 128) * NHW + n4);
    float4 xs3 = *(const float4*)(bb + (size_t)(c_l + 192) * NHW + n4);

    // packed-weight base for this wave's co eighth (frag = wave*2 + ct)
    const unsigned short* kbase = kpk + (size_t)(wave * 2) * 512 + lane * 8;
    const unsigned short* qbase = qpk + (size_t)(wave * 2) * 512 + lane * 8;

    // weight prologue: chunks 0,1 -> bufs 0,1 (overlaps staging latency)
    short8 wK[3][2], wQ[3][2];
    #pragma unroll
    for (int ct = 0; ct < 2; ++ct) {
        wK[0][ct] = *(const short8*)(kbase + ct * 512);
        wQ[0][ct] = *(const short8*)(qbase + ct * 512);
        wK[1][ct] = *(const short8*)(kbase + 8192 + ct * 512);
        wQ[1][ct] = *(const short8*)(qbase + 8192 + ct * 512);
    }

    // CONSUME staging: convert, v-acc, LDS write
    #define CONSUME(XS, CI)                                                  \
    {                                                                        \
        int c0 = (CI) + c_l;                                                 \
        ushort4 o0;                                                          \
        o0.x = f2bf(XS.x); o0.y = f2bf(XS.y);                                \
        o0.z = f2bf(XS.z); o0.w = f2bf(XS.w);                                \
        float w0 = value_w[c0];                                              \
        vacc.x += XS.x * w0; vacc.y += XS.y * w0;                            \
        vacc.z += XS.z * w0; vacc.w += XS.w * w0;                            \
        Xs[n4 + 0][c0] = o0.x; Xs[n4 + 1][c0] = o0.y;                        \
        Xs[n4 + 2][c0] = o0.z; Xs[n4 + 3][c0] = o0.w;                        \
    }
    CONSUME(xs0, 0)
    CONSUME(xs1, 64)
    CONSUME(xs2, 128)
    CONSUME(xs3, 192)
    #undef CONSUME
    __syncthreads();

    f32x4 accK[2][2], accQ[2][2];            // [ns][ct]
    #pragma unroll
    for (int ct = 0; ct < 2; ++ct) {
        int co = wave * 32 + ct * 16 + l15;
        float bK = key_b[co], bQ = query_b[co];
        accK[0][ct] = (f32x4){bK, bK, bK, bK};
        accK[1][ct] = (f32x4){bK, bK, bK, bK};
        accQ[0][ct] = (f32x4){bQ, bQ, bQ, bQ};
        accQ[1][ct] = (f32x4){bQ, bQ, bQ, bQ};
    }

    // 8 k-chunks, fully unrolled, no barriers; depth-2 weight prefetch
    #pragma unroll
    for (int g = 0; g < 8; ++g) {
        if (g < 6) {
            const int nb_ = (g + 2) % 3;
            #pragma unroll
            for (int ct = 0; ct < 2; ++ct) {
                wK[nb_][ct] = *(const short8*)(kbase + (g + 2) * 8192 + ct * 512);
                wQ[nb_][ct] = *(const short8*)(qbase + (g + 2) * 8192 + ct * 512);
            }
        }
        short8 af0 = *(const short8*)&Xs[l15][g * 32 + quad * 8];
        short8 af1 = *(const short8*)&Xs[16 + l15][g * 32 + quad * 8];
        const int cb = g % 3;
        #pragma unroll
        for (int ct = 0; ct < 2; ++ct) {
            accK[0][ct] = __builtin_amdgcn_mfma_f32_16x16x32_bf16(af0, wK[cb][ct], accK[0][ct], 0, 0, 0);
            accK[1][ct] = __builtin_amdgcn_mfma_f32_16x16x32_bf16(af1, wK[cb][ct], accK[1][ct], 0, 0, 0);
            accQ[0][ct] = __builtin_amdgcn_mfma_f32_16x16x32_bf16(af0, wQ[cb][ct], accQ[0][ct], 0, 0, 0);
            accQ[1][ct] = __builtin_amdgcn_mfma_f32_16x16x32_bf16(af1, wQ[cb][ct], accQ[1][ct], 0, 0, 0);
        }
    }

    // v: c_l = wave*8 + (lane>>3) -> reduce over lane bits 3..5, waves via LDS
    #pragma unroll
    for (int o = 8; o <= 32; o <<= 1) {
        vacc.x += __shfl_xor(vacc.x, o, 64); vacc.y += __shfl_xor(vacc.y, o, 64);
        vacc.z += __shfl_xor(vacc.z, o, 64); vacc.w += __shfl_xor(vacc.w, o, 64);
    }

    // row-norm partials: rows n = n0 + ns*16 + quad*4 + r, this wave's 32 co
    float nK[2][4] = {{0, 0, 0, 0}, {0, 0, 0, 0}};
    float nQ[2][4] = {{0, 0, 0, 0}, {0, 0, 0, 0}};
    #pragma unroll
    for (int ns = 0; ns < 2; ++ns)
        #pragma unroll
        for (int ct = 0; ct < 2; ++ct)
            #pragma unroll
            for (int r = 0; r < 4; ++r) {
                nK[ns][r] += accK[ns][ct][r] * accK[ns][ct][r];
                nQ[ns][r] += accQ[ns][ct][r] * accQ[ns][ct][r];
            }
    #pragma unroll
    for (int ns = 0; ns < 2; ++ns)
        #pragma unroll
        for (int r = 0; r < 4; ++r)
            #pragma unroll
            for (int o = 1; o < 16; o <<= 1) {
                nK[ns][r] += __shfl_xor(nK[ns][r], o, 64);
                nQ[ns][r] += __shfl_xor(nQ[ns][r], o, 64);
            }
    if (l15 == 0)
        #pragma unroll
        for (int ns = 0; ns < 2; ++ns)
            #pragma unroll
            for (int r = 0; r < 4; ++r) {
                PK[wave][ns][quad * 4 + r] = nK[ns][r];
                PQ[wave][ns][quad * 4 + r] = nQ[ns][r];
            }
    if (lane < 8) vred[wave][lane] = vacc;
    __syncthreads();

    float ik[2][4], iq[2][4];
    #pragma unroll
    for (int ns = 0; ns < 2; ++ns)
        #pragma unroll
        for (int r = 0; r < 4; ++r) {
            int qr = quad * 4 + r;
            float sk = 0.f, sq = 0.f;
            #pragma unroll
            for (int w = 0; w < 8; ++w) { sk += PK[w][ns][qr]; sq += PQ[w][ns][qr]; }
            ik[ns][r] = 1.f / fmaxf(sqrtf(sk), 1e-12f);
            iq[ns][r] = 1.f / fmaxf(sqrtf(sq), 1e-12f);
        }
    #pragma unroll
    for (int ns = 0; ns < 2; ++ns)
        #pragma unroll
        for (int ct = 0; ct < 2; ++ct)
            #pragma unroll
            for (int r = 0; r < 4; ++r) {
                size_t row = (size_t)(b * NHW + n0 + ns * 16 + quad * 4 + r) * NC
                           + wave * 32 + ct * 16 + l15;
                Kn[row] = f2bf(accK[ns][ct][r] * ik[ns][r]);
                Qn[row] = f2bf(accQ[ns][ct][r] * iq[ns][r]);
            }
    if (t < 8) {
        float4 s = {0.f, 0.f, 0.f, 0.f};
        #pragma unroll
        for (int w = 0; w < 8; ++w) {
            float4 p = vred[w][t];
            s.x += p.x; s.y += p.y; s.z += p.z; s.w += p.w;
        }
        float vb = value_b[0];
        s.x += vb; s.y += vb; s.z += vb; s.w += vb;
        *(float4*)(vout + b * NHW + n0 + t * 4) = s;
    }
}

// Per (b, 64 m-cols): 8 waves each own an n-eighth; per-iter 32 MFMAs in
// 8 independent depth-4 chains. XCD-swizzled 1D grid: all 16 m-blocks of a
// given b land on ONE XCD (i%8), so Kn[b]+Qn[b] (1 MB) stays in its 4 MB L2.
__global__ __launch_bounds__(512) void attn_kernel(
    const unsigned short* __restrict__ Kn,
    const unsigned short* __restrict__ Qn,
    const float* __restrict__ vbuf,
    float* __restrict__ R)
{
    const int i = blockIdx.x;                  // 0..255
    const int b  = ((i & 7) << 1) | (i >> 7);  // XCD = i%8 -> b fixed per XCD
    const int m0 = ((i >> 3) & 15) * 64;
    const int t = threadIdx.x, wave = t >> 6, lane = t & 63;
    const int l15 = lane & 15, quad = lane >> 4;

    short8 bf[4][8];
    #pragma unroll
    for (int ms = 0; ms < 4; ++ms) {
        const short* q = (const short*)Qn
                       + (size_t)(b * NHW + m0 + ms * 16 + l15) * NC + quad * 8;
        #pragma unroll
        for (int c = 0; c < 8; ++c) bf[ms][c] = *(const short8*)(q + 32 * c);
    }
    const float* vb = vbuf + b * NHW;
    const int nstart = wave * 128;
    const short* ka = (const short*)Kn + (size_t)(b * NHW + nstart + l15) * NC + quad * 8;

    float z[4] = {0.f, 0.f, 0.f, 0.f}, tc[4] = {0.f, 0.f, 0.f, 0.f};
    for (int it = 0; it < 8; ++it, ka += 16 * NC) {
        short8 af[8];
        #pragma unroll
        for (int c = 0; c < 8; ++c) af[c] = *(const short8*)(ka + 32 * c);
        f32x4 a0[4], a1[4];
        #pragma unroll
        for (int ms = 0; ms < 4; ++ms) { a0[ms] = (f32x4){0,0,0,0}; a1[ms] = (f32x4){0,0,0,0}; }
        #pragma unroll
        for (int c = 0; c < 4; ++c)
            #pragma unroll
            for (int ms = 0; ms < 4; ++ms) {
                a0[ms] = __builtin_amdgcn_mfma_f32_16x16x32_bf16(af[c],     bf[ms][c],     a0[ms], 0, 0, 0);
                a1[ms] = __builtin_amdgcn_mfma_f32_16x16x32_bf16(af[c + 4], bf[ms][c + 4], a1[ms], 0, 0, 0);
            }
        float4 vv = *(const float4*)(vb + nstart + it * 16 + quad * 4);
        #pragma unroll
        for (int ms = 0; ms < 4; ++ms)
            #pragma unroll
            for (int r = 0; r < 4; ++r) {
                float e = __expf(a0[ms][r] + a1[ms][r]);
                z[ms] += e;
                tc[ms] += ((const float*)&vv)[r] * e;
            }
    }
    #pragma unroll
    for (int ms = 0; ms < 4; ++ms) {
        z[ms]  += __shfl_xor(z[ms], 16, 64);  z[ms]  += __shfl_xor(z[ms], 32, 64);
        tc[ms] += __shfl_xor(tc[ms], 16, 64); tc[ms] += __shfl_xor(tc[ms], 32, 64);
    }

    __shared__ float zs[8][4][16], ts[8][4][16];
    if (lane < 16)
        #pragma unroll
        for (int ms = 0; ms < 4; ++ms) {
            zs[wave][ms][l15] = z[ms];
            ts[wave][ms][l15] = tc[ms];
        }
    __syncthreads();
    if (t < 64) {
        int ms = t >> 4, li = t & 15;
        float zz = 0.f, tt = 0.f;
        #pragma unroll
        for (int w = 0; w < 8; ++w) { zz += zs[w][ms][li]; tt += ts[w][ms][li]; }
        R[b * NHW + m0 + ms * 16 + li] = tt / zz;
    }
}

// out[b,c,i,j] = 3x3 box sum over P[m] = R[b,m]*batch[b,c,m]  (fp32, L3-hot)
__global__ __launch_bounds__(256) void out_kernel(
    const float* __restrict__ batch,
    const float* __restrict__ R,
    float* __restrict__ out)
{
    const int bc = blockIdx.x;
    const int b  = bc >> 8;
    const int t  = threadIdx.x;
    __shared__ float P[NHW];

    const float* xp = batch + (size_t)bc * NHW;
    const float* rp = R + b * NHW;
    {
        float4 xv = *(const float4*)(xp + t * 4);
        float4 rv = *(const float4*)(rp + t * 4);
        P[t * 4 + 0] = rv.x * xv.x;
        P[t * 4 + 1] = rv.y * xv.y;
        P[t * 4 + 2] = rv.z * xv.z;
        P[t * 4 + 3] = rv.w * xv.w;
    }
    __syncthreads();
    for (int idx = t; idx < NCH * NCH; idx += 256) {
        int i = idx / NCH, j = idx - i * NCH;
        const float* pr = &P[i * 32 + j];
        float s = pr[0]  + pr[1]  + pr[2]
                + pr[32] + pr[33] + pr[34]
                + pr[64] + pr[65] + pr[66];
        out[(size_t)bc * (NCH * NCH) + idx] = s;
    }
}

extern "C" void kernel_launch(void* const* d_in, const int* in_sizes, int n_in,
                              void* d_out, int out_size, void* d_ws, size_t ws_size,
                              hipStream_t stream) {
    const float* batch   = (const float*)d_in[0];
    const float* key_w   = (const float*)d_in[1];
    const float* key_b   = (const float*)d_in[2];
    const float* query_w = (const float*)d_in[3];
    const float* query_b = (const float*)d_in[4];
    const float* value_w = (const float*)d_in[5];
    const float* value_b = (const float*)d_in[6];
    float* out = (float*)d_out;

    char* ws = (char*)d_ws;
    const size_t KQ = (size_t)NB * NHW * NC;            // 4,194,304 elems
    unsigned short* Kn  = (unsigned short*)ws;                        // 8MB
    unsigned short* Qn  = Kn + KQ;                                    // 8MB
    unsigned short* kpk = Qn + KQ;                                    // 128KB
    unsigned short* qpk = kpk + NC * NC;                              // 128KB
    float* vbuf = (float*)(qpk + NC * NC);                            // 64KB
    float* Rbuf = vbuf + NB * NHW;                                    // 64KB

    wconv_kernel<<<16, 256, 0, stream>>>(key_w, query_w, kpk, qpk);
    fused_lin_kernel<<<dim3(32, NB), 512, 0, stream>>>(batch, value_w, value_b,
                                                       kpk, qpk, key_b, query_b,
                                                       Kn, Qn, vbuf);
    attn_kernel<<<256, 512, 0, stream>>>(Kn, Qn, vbuf, Rbuf);
    out_kernel<<<NB * NC, 256, 0, stream>>>(batch, Rbuf, out);
}